// Round 1
// baseline (2572.372 us; speedup 1.0000x reference)
//
#include <hip/hip_runtime.h>
#include <stdint.h>

#define DEV static __device__ __forceinline__

typedef __attribute__((ext_vector_type(4))) float f32x4;
typedef __attribute__((ext_vector_type(8))) short bf16x8;
typedef __attribute__((ext_vector_type(4))) short s16x4;

// dims
static constexpr int L_ = 6, T_ = 128, NE = 32, D_ = 1024, H_ = 16, DH_ = 64, M_ = 128, DI_ = 4096;
static constexpr int KLEN = M_ + T_;   // 256
static constexpr int TN = T_ * NE;     // 4096
static constexpr int NB = NE * H_;     // 512 attention batches

DEV unsigned short f2bf(float f) {
  unsigned u = __builtin_bit_cast(unsigned, f);
  u += 0x7FFFu + ((u >> 16) & 1u);
  return (unsigned short)(u >> 16);
}
DEV float bf2f(unsigned short h) {
  unsigned u = ((unsigned)h) << 16;
  return __builtin_bit_cast(float, u);
}

DEV void gload16(const unsigned short* g, unsigned short* lds) {
  __builtin_amdgcn_global_load_lds(
      (const __attribute__((address_space(1))) unsigned int*)g,
      (__attribute__((address_space(3))) unsigned int*)lds, 16, 0, 0);
}

// ---------------------------------------------------------------------------
// Generic batched bf16 GEMM: C[M,N] = A[M,K] @ Bt[N,K]  (Bt row-major N x K)
// tile 128x128, BK=64, 4 waves (2x2), mfma_f32_16x16x32_bf16.
// Batch z -> (bn = z/Hb, bh = z%Hb); per-batch offsets bn*sAn + bh*sAh etc.
// EPI: 0=f32 out, 1=bf16 out, 2=bf16(bias+relu), 3=f32(bias)
// ---------------------------------------------------------------------------
template <int EPI>
__global__ __launch_bounds__(256) void gemm_bt(
    const unsigned short* __restrict__ A, int lda, int sAn, int sAh,
    const unsigned short* __restrict__ B, int ldb, int sBn, int sBh,
    void* __restrict__ Cv, int ldc, int sC,
    const float* __restrict__ bias, int nK, int Hb)
{
  __shared__ unsigned short lA[128 * 64];
  __shared__ unsigned short lB[128 * 64];

  const int z = blockIdx.z;
  const int bn = z / Hb, bh = z % Hb;
  const unsigned short* Ab = A + bn * sAn + bh * sAh;
  const unsigned short* Bb = B + bn * sBn + bh * sBh;
  const int m0 = blockIdx.y * 128;
  const int n0 = blockIdx.x * 128;

  const int t = threadIdx.x;
  const int w = t >> 6, l = t & 63;
  const int wr = (w >> 1) * 64, wc = (w & 1) * 64;
  const int lan = l & 15, lgr = l >> 4;

  f32x4 acc[4][4];
#pragma unroll
  for (int m = 0; m < 4; ++m)
#pragma unroll
    for (int n = 0; n < 4; ++n) acc[m][n] = (f32x4){0.f, 0.f, 0.f, 0.f};

  for (int kt = 0; kt < nK; ++kt) {
    const int k0 = kt * 64;
    __syncthreads();
#pragma unroll
    for (int i = 0; i < 4; ++i) {
      const int obb = i * 4096 + w * 1024;   // wave-uniform byte base in tile
      const int ob  = obb + (l << 4);        // this lane's byte offset
      const int row = ob >> 7;               // 128 B per row (64 bf16)
      const int col = (ob & 127) >> 1;
      gload16(Ab + (m0 + row) * lda + k0 + col, lA + (obb >> 1));
      gload16(Bb + (n0 + row) * ldb + k0 + col, lB + (obb >> 1));
    }
    asm volatile("s_waitcnt vmcnt(0)" ::: "memory");
    __syncthreads();

#pragma unroll
    for (int ks = 0; ks < 2; ++ks) {
      const int kOff = ks * 32 + (lgr << 3);
      bf16x8 av[4], bv[4];
#pragma unroll
      for (int m = 0; m < 4; ++m)
        av[m] = *(const bf16x8*)&lA[(wr + m * 16 + lan) * 64 + kOff];
#pragma unroll
      for (int n = 0; n < 4; ++n)
        bv[n] = *(const bf16x8*)&lB[(wc + n * 16 + lan) * 64 + kOff];
#pragma unroll
      for (int m = 0; m < 4; ++m)
#pragma unroll
        for (int n = 0; n < 4; ++n)
          acc[m][n] = __builtin_amdgcn_mfma_f32_16x16x32_bf16(av[m], bv[n], acc[m][n], 0, 0, 0);
    }
  }

  const int zc = z * sC;
#pragma unroll
  for (int m = 0; m < 4; ++m) {
    const int row = m0 + wr + m * 16 + lgr * 4;
#pragma unroll
    for (int n = 0; n < 4; ++n) {
      const int col = n0 + wc + n * 16 + lan;
      const float bcol = (EPI >= 2) ? bias[col] : 0.f;
#pragma unroll
      for (int e = 0; e < 4; ++e) {
        float v = acc[m][n][e];
        const int idx = zc + (row + e) * ldc + col;
        if (EPI == 0) {
          ((float*)Cv)[idx] = v;
        } else if (EPI == 1) {
          ((unsigned short*)Cv)[idx] = f2bf(v);
        } else if (EPI == 2) {
          v += bcol; v = v > 0.f ? v : 0.f;
          ((unsigned short*)Cv)[idx] = f2bf(v);
        } else {
          ((float*)Cv)[idx] = v + bcol;
        }
      }
    }
  }
}

// ---------------------------------------------------------------------------
// PV: per batch z=(nn,hh): O[i,d] = sum_j P[i,j] * V[j,d]
// P: [512][128][256] bf16 ; V: bf16 [(j*32+nn)*1024 + hh*64 + d]
// O: bf16 [(i*32+nn)*1024 + hh*64 + d]
// ---------------------------------------------------------------------------
__global__ __launch_bounds__(256) void pv_kernel(
    const unsigned short* __restrict__ P, const unsigned short* __restrict__ V,
    unsigned short* __restrict__ O)
{
  const int z = blockIdx.x;
  const int nn = z >> 4, hh = z & 15;
  const int t = threadIdx.x, w = t >> 6, l = t & 63;
  const int lan = l & 15, lgr = l >> 4;
  const int i0 = w * 32;
  const unsigned short* Pz = P + z * (T_ * KLEN);
  const unsigned short* Vz = V + hh * DH_;

  f32x4 acc[2][4];
#pragma unroll
  for (int m = 0; m < 2; ++m)
#pragma unroll
    for (int n = 0; n < 4; ++n) acc[m][n] = (f32x4){0.f, 0.f, 0.f, 0.f};

  for (int ks = 0; ks < 8; ++ks) {
    const int kb = ks * 32 + lgr * 8;   // j base for this lane's fragments
    bf16x8 bv[4];
#pragma unroll
    for (int n = 0; n < 4; ++n) {
      const int d = n * 16 + lan;
      bf16x8 tmp;
#pragma unroll
      for (int jj = 0; jj < 8; ++jj)
        tmp[jj] = (short)Vz[((kb + jj) * NE + nn) * 1024 + d];
      bv[n] = tmp;
    }
    bf16x8 av[2];
#pragma unroll
    for (int m = 0; m < 2; ++m)
      av[m] = *(const bf16x8*)&Pz[(i0 + m * 16 + lan) * KLEN + kb];
#pragma unroll
    for (int m = 0; m < 2; ++m)
#pragma unroll
      for (int n = 0; n < 4; ++n)
        acc[m][n] = __builtin_amdgcn_mfma_f32_16x16x32_bf16(av[m], bv[n], acc[m][n], 0, 0, 0);
  }
#pragma unroll
  for (int m = 0; m < 2; ++m)
#pragma unroll
    for (int n = 0; n < 4; ++n)
#pragma unroll
      for (int e = 0; e < 4; ++e) {
        const int i = i0 + m * 16 + lgr * 4 + e;
        const int d = n * 16 + lan;
        O[(i * NE + nn) * 1024 + hh * DH_ + d] = f2bf(acc[m][n][e]);
      }
}

// ---------------------------------------------------------------------------
// Masked softmax with rel_shift gather. One wave per (z, i) row.
// S[i][j] = (AC[i][j] + BD[i][j+127-i]) * 0.125, masked, softmax over j=0..255
// ---------------------------------------------------------------------------
__global__ __launch_bounds__(256) void softmax_kernel(
    const unsigned short* __restrict__ AC, const unsigned short* __restrict__ BD,
    const int* __restrict__ ep, unsigned short* __restrict__ P)
{
  const int g = blockIdx.x * 4 + (threadIdx.x >> 6);
  const int l = threadIdx.x & 63;
  const int z = g >> 7, i = g & 127;
  const int nn = z >> 4;
  const int base = z * (T_ * KLEN) + i * KLEN;
  const int j0 = l * 4;
  const int epi = ep[i * NE + nn];
  s16x4 ac4 = *(const s16x4*)&AC[base + j0];
  float sc[4];
#pragma unroll
  for (int q = 0; q < 4; ++q) {
    const int j = j0 + q;
    int jx = j + (T_ - 1) - i; if (jx > KLEN - 1) jx = KLEN - 1;
    const float bd = bf2f((unsigned short)BD[base + jx]);
    bool allow;
    if (j < M_) {
      allow = (epi == 0);
    } else {
      const int jp = j - M_;
      allow = (jp <= i) && (ep[jp * NE + nn] == epi);
    }
    const float v = (bf2f((unsigned short)ac4[q]) + bd) * 0.125f;
    sc[q] = allow ? v : -1e9f;
  }
  float mx = fmaxf(fmaxf(sc[0], sc[1]), fmaxf(sc[2], sc[3]));
#pragma unroll
  for (int o = 32; o; o >>= 1) mx = fmaxf(mx, __shfl_xor(mx, o));
  float p[4], sum = 0.f;
#pragma unroll
  for (int q = 0; q < 4; ++q) { p[q] = __expf(sc[q] - mx); sum += p[q]; }
#pragma unroll
  for (int o = 32; o; o >>= 1) sum += __shfl_xor(sum, o);
  const float inv = 1.f / sum;
  s16x4 o4;
#pragma unroll
  for (int q = 0; q < 4; ++q) o4[q] = (short)f2bf(p[q] * inv);
  *(s16x4*)&P[base + j0] = o4;
}

// ---------------------------------------------------------------------------
// W (Kd x Nd, f32 row-major) -> WT (Nd x Kd, bf16 row-major)
// ---------------------------------------------------------------------------
__global__ __launch_bounds__(256) void transpose_kernel(
    const float* __restrict__ W, unsigned short* __restrict__ WT, int Kd, int Nd)
{
  __shared__ float tile[32][33];
  const int tx = threadIdx.x & 31, ty = threadIdx.x >> 5;
  const int nIn = blockIdx.x * 32 + tx;
  const int kBase = blockIdx.y * 32;
#pragma unroll
  for (int r = 0; r < 32; r += 8)
    tile[ty + r][tx] = W[(kBase + ty + r) * Nd + nIn];
  __syncthreads();
#pragma unroll
  for (int r = 0; r < 32; r += 8)
    WT[(blockIdx.x * 32 + ty + r) * Kd + kBase + tx] = f2bf(tile[tx][ty + r]);
}

// q (f32, TN x 1024) + r_w_bias / r_r_bias (flat 1024 over (h,dh)) -> bf16
__global__ __launch_bounds__(256) void qbias_kernel(
    const float* __restrict__ q, const float* __restrict__ rwb, const float* __restrict__ rrb,
    unsigned short* __restrict__ qw, unsigned short* __restrict__ qr)
{
  const int idx = blockIdx.x * 256 + threadIdx.x;
  const int c = idx & 1023;
  const float v = q[idx];
  qw[idx] = f2bf(v + rwb[c]);
  qr[idx] = f2bf(v + rrb[c]);
}

// cat lower half: cat[(j*32+nn)*1024 + d] = bf16(mems_l[nn][j][d] * masks[nn])
__global__ __launch_bounds__(256) void catmem_kernel(
    const float* __restrict__ mems_l, const float* __restrict__ masks,
    unsigned short* __restrict__ cat)
{
  const int idx = blockIdx.x * 256 + threadIdx.x;  // 4M elements
  const int d = idx & 1023;
  const int r = idx >> 10;      // j*32+nn
  const int nn = r & 31, j = r >> 5;
  const float mk0 = masks[nn];
  cat[idx] = f2bf(mems_l[(nn * M_ + j) * 1024 + d] * mk0);
}

// h = x + ctx (f32) and cat upper half (bf16)
__global__ __launch_bounds__(256) void hprep_kernel(
    const float* __restrict__ x, const float* __restrict__ ctx,
    float* __restrict__ h, unsigned short* __restrict__ catUp)
{
  const int idx = blockIdx.x * 256 + threadIdx.x;
  const float v = x[idx] + ctx[idx];
  h[idx] = v;
  catUp[idx] = f2bf(v);
}

// sinusoidal relative position table, bf16 (KLEN x 1024)
__global__ __launch_bounds__(256) void rpos_kernel(unsigned short* __restrict__ R)
{
  const int idx = blockIdx.x * 256 + threadIdx.x;   // 262144
  const int d = idx & 1023, j = idx >> 10;
  const float pos = (float)(KLEN - 1 - j);
  const int f = d & 511;
  const float inv_freq = __expf(-((float)(2 * f) * (1.f / 1024.f)) * 9.210340371976184f);
  const float ang = pos * inv_freq;
  const float v = (d < 512) ? sinf(ang) : cosf(ang);
  R[idx] = f2bf(v);
}

// episode counters: ep[i*32+nn] = #resets (mask==0) in steps 0..i
__global__ void ep_kernel(const float* __restrict__ masks, int* __restrict__ ep)
{
  const int nn = threadIdx.x;
  if (nn < NE) {
    int c = 0;
    for (int i = 0; i < T_; ++i) {
      c += (masks[i * NE + nn] == 0.f) ? 1 : 0;
      ep[i * NE + nn] = c;
    }
  }
}

// y = LN(a + bres) * g + b ; writes f32 (outf) and optional bf16 (outbf)
__global__ __launch_bounds__(256) void ln_kernel(
    const float* __restrict__ a, const float* __restrict__ bres,
    const float* __restrict__ g, const float* __restrict__ bb,
    float* __restrict__ outf, unsigned short* __restrict__ outbf)
{
  const int row = blockIdx.x;
  const int t = threadIdx.x, w = t >> 6, l = t & 63;
  const int c = t * 4;
  const int base = row * 1024;
  f32x4 va = *(const f32x4*)&a[base + c];
  f32x4 vb = *(const f32x4*)&bres[base + c];
  f32x4 v = va + vb;
  float s = v[0] + v[1] + v[2] + v[3];
#pragma unroll
  for (int o = 32; o; o >>= 1) s += __shfl_xor(s, o);
  __shared__ float red[8];
  if (l == 0) red[w] = s;
  __syncthreads();
  s = red[0] + red[1] + red[2] + red[3];
  const float mu = s * (1.f / 1024.f);
  f32x4 dv = v - mu;
  float s2 = dv[0]*dv[0] + dv[1]*dv[1] + dv[2]*dv[2] + dv[3]*dv[3];
#pragma unroll
  for (int o = 32; o; o >>= 1) s2 += __shfl_xor(s2, o);
  if (l == 0) red[4 + w] = s2;
  __syncthreads();
  s2 = red[4] + red[5] + red[6] + red[7];
  const float inv = rsqrtf(s2 * (1.f / 1024.f) + 1e-5f);
  f32x4 y;
#pragma unroll
  for (int q = 0; q < 4; ++q) y[q] = dv[q] * inv * g[c + q] + bb[c + q];
  *(f32x4*)&outf[base + c] = y;
  if (outbf) {
    s16x4 o4;
#pragma unroll
    for (int q = 0; q < 4; ++q) o4[q] = (short)f2bf(y[q]);
    *(s16x4*)&outbf[base + c] = o4;
  }
}

// ---------------------------------------------------------------------------
extern "C" void kernel_launch(void* const* d_in, const int* in_sizes, int n_in,
                              void* d_out, int out_size, void* d_ws, size_t ws_size,
                              hipStream_t stream)
{
  (void)in_sizes; (void)n_in; (void)out_size; (void)ws_size;
  const float* x    = (const float*)d_in[0];
  const float* ctx  = (const float*)d_in[1];
  const float* mems = (const float*)d_in[2];
  const float* masks= (const float*)d_in[3];
  const float* Wq   = (const float*)d_in[4];
  const float* Wk   = (const float*)d_in[5];
  const float* Wv   = (const float*)d_in[6];
  const float* Wr   = (const float*)d_in[7];
  const float* Wo   = (const float*)d_in[8];
  const float* W1   = (const float*)d_in[9];
  const float* b1   = (const float*)d_in[10];
  const float* W2   = (const float*)d_in[11];
  const float* b2   = (const float*)d_in[12];
  const float* ln1g = (const float*)d_in[13];
  const float* ln1b = (const float*)d_in[14];
  const float* ln2g = (const float*)d_in[15];
  const float* ln2b = (const float*)d_in[16];
  const float* rwb  = (const float*)d_in[17];
  const float* rrb  = (const float*)d_in[18];

  char* ws = (char*)d_ws;
  size_t off = 0;
  auto alloc = [&](size_t bytes) {
    char* p = ws + off;
    off += (bytes + 255) & ~(size_t)255;
    return p;
  };
  unsigned short* wtq = (unsigned short*)alloc(1024u * 1024 * 2);
  unsigned short* wtk = (unsigned short*)alloc(1024u * 1024 * 2);
  unsigned short* wtv = (unsigned short*)alloc(1024u * 1024 * 2);
  unsigned short* wtr = (unsigned short*)alloc(1024u * 1024 * 2);
  unsigned short* wto = (unsigned short*)alloc(1024u * 1024 * 2);
  unsigned short* wt1 = (unsigned short*)alloc(4096u * 1024 * 2);
  unsigned short* wt2 = (unsigned short*)alloc(4096u * 1024 * 2);
  unsigned short* cat = (unsigned short*)alloc((size_t)KLEN * NE * 1024 * 2);   // 16MB
  unsigned short* Rbf = (unsigned short*)alloc((size_t)KLEN * 1024 * 2);
  unsigned short* rbf = (unsigned short*)alloc((size_t)KLEN * 1024 * 2);
  int*            epb = (int*)alloc((size_t)T_ * NE * 4);
  float*          h   = (float*)alloc((size_t)TN * 1024 * 4);
  float*          h1  = (float*)alloc((size_t)TN * 1024 * 4);
  float*          qf  = (float*)alloc((size_t)TN * 1024 * 4);                  // also o_f32
  unsigned short* qw  = (unsigned short*)alloc((size_t)TN * 1024 * 2);         // also h1_bf
  unsigned short* qr  = (unsigned short*)alloc((size_t)TN * 1024 * 2);
  unsigned short* kbf = (unsigned short*)alloc((size_t)KLEN * NE * 1024 * 2);
  unsigned short* vbf = (unsigned short*)alloc((size_t)KLEN * NE * 1024 * 2);
  unsigned short* ACb = (unsigned short*)alloc((size_t)NB * T_ * KLEN * 2);    // also f1_bf
  unsigned short* BDb = (unsigned short*)alloc((size_t)NB * T_ * KLEN * 2);    // also f2_f32
  unsigned short* Pb  = (unsigned short*)alloc((size_t)NB * T_ * KLEN * 2);
  unsigned short* obf = (unsigned short*)alloc((size_t)TN * 1024 * 2);

  float* of32 = qf;                 // alias (q dead after qbias)
  unsigned short* f1 = ACb;         // alias (AC dead after softmax)
  float* f2 = (float*)BDb;          // alias (BD dead after softmax)
  unsigned short* h1bf = qw;        // alias (qw dead after AC gemm)
  unsigned short* catUp = cat + (size_t)M_ * NE * 1024;

  rpos_kernel<<<KLEN * 1024 / 256, 256, 0, stream>>>(Rbf);
  ep_kernel<<<1, 64, 0, stream>>>(masks, epb);
  hprep_kernel<<<TN * 1024 / 256, 256, 0, stream>>>(x, ctx, h, catUp);

  for (int l = 0; l < L_; ++l) {
    const size_t wOff = (size_t)l * 1024 * 1024;
    const size_t wOffBig = (size_t)l * 1024 * 4096;
    transpose_kernel<<<dim3(32, 32), 256, 0, stream>>>(Wq + wOff, wtq, 1024, 1024);
    transpose_kernel<<<dim3(32, 32), 256, 0, stream>>>(Wk + wOff, wtk, 1024, 1024);
    transpose_kernel<<<dim3(32, 32), 256, 0, stream>>>(Wv + wOff, wtv, 1024, 1024);
    transpose_kernel<<<dim3(32, 32), 256, 0, stream>>>(Wr + wOff, wtr, 1024, 1024);
    transpose_kernel<<<dim3(32, 32), 256, 0, stream>>>(Wo + wOff, wto, 1024, 1024);
    transpose_kernel<<<dim3(128, 32), 256, 0, stream>>>(W1 + wOffBig, wt1, 1024, 4096);
    transpose_kernel<<<dim3(32, 128), 256, 0, stream>>>(W2 + wOffBig, wt2, 4096, 1024);
    catmem_kernel<<<M_ * NE * 1024 / 256, 256, 0, stream>>>(
        mems + (size_t)l * NE * M_ * 1024, masks, cat);

    // k, v, q, r projections
    gemm_bt<1><<<dim3(8, 64, 1), 256, 0, stream>>>(cat, 1024, 0, 0, wtk, 1024, 0, 0,
                                                   kbf, 1024, 0, nullptr, 16, 1);
    gemm_bt<1><<<dim3(8, 64, 1), 256, 0, stream>>>(cat, 1024, 0, 0, wtv, 1024, 0, 0,
                                                   vbf, 1024, 0, nullptr, 16, 1);
    gemm_bt<0><<<dim3(8, 32, 1), 256, 0, stream>>>(catUp, 1024, 0, 0, wtq, 1024, 0, 0,
                                                   qf, 1024, 0, nullptr, 16, 1);
    gemm_bt<1><<<dim3(8, 2, 1), 256, 0, stream>>>(Rbf, 1024, 0, 0, wtr, 1024, 0, 0,
                                                  rbf, 1024, 0, nullptr, 16, 1);
    qbias_kernel<<<TN * 1024 / 256, 256, 0, stream>>>(qf, rwb, rrb, qw, qr);

    // AC / BD batched score GEMMs (batch z = nn*16+hh), K=64, M=128, N=256
    gemm_bt<1><<<dim3(2, 1, NB), 256, 0, stream>>>(qw, NE * 1024, 1024, 64,
                                                   kbf, NE * 1024, 1024, 64,
                                                   ACb, KLEN, T_ * KLEN, nullptr, 1, H_);
    gemm_bt<1><<<dim3(2, 1, NB), 256, 0, stream>>>(qr, NE * 1024, 1024, 64,
                                                   rbf, 1024, 0, 64,
                                                   BDb, KLEN, T_ * KLEN, nullptr, 1, H_);
    softmax_kernel<<<NB * T_ / 4, 256, 0, stream>>>(ACb, BDb, epb, Pb);
    pv_kernel<<<NB, 256, 0, stream>>>(Pb, vbf, obf);

    // output projection + LN1
    gemm_bt<0><<<dim3(8, 32, 1), 256, 0, stream>>>(obf, 1024, 0, 0, wto, 1024, 0, 0,
                                                   of32, 1024, 0, nullptr, 16, 1);
    ln_kernel<<<TN, 256, 0, stream>>>(h, of32, ln1g + l * 1024, ln1b + l * 1024, h1, h1bf);

    // FFN
    gemm_bt<2><<<dim3(32, 32, 1), 256, 0, stream>>>(h1bf, 1024, 0, 0, wt1, 1024, 0, 0,
                                                    f1, 4096, 0, b1 + l * 4096, 16, 1);
    gemm_bt<3><<<dim3(8, 32, 1), 256, 0, stream>>>(f1, 4096, 0, 0, wt2, 4096, 0, 0,
                                                   f2, 1024, 0, b2 + l * 1024, 64, 1);
    ln_kernel<<<TN, 256, 0, stream>>>(h1, f2, ln2g + l * 1024, ln2b + l * 1024,
                                      (l == L_ - 1) ? (float*)d_out : h, catUp);
  }
}

// Round 2
// 1987.263 us; speedup vs baseline: 1.2944x; 1.2944x over previous
//
#include <hip/hip_runtime.h>
#include <stdint.h>

#define DEV static __device__ __forceinline__

typedef __attribute__((ext_vector_type(4))) float f32x4;
typedef __attribute__((ext_vector_type(8))) short bf16x8;
typedef __attribute__((ext_vector_type(4))) short s16x4;

// dims
static constexpr int L_ = 6, T_ = 128, NE = 32, D_ = 1024, H_ = 16, DH_ = 64, M_ = 128, DI_ = 4096;
static constexpr int KLEN = M_ + T_;   // 256
static constexpr int TN = T_ * NE;     // 4096
static constexpr int NB = NE * H_;     // 512 attention batches

DEV unsigned short f2bf(float f) {
  unsigned u = __builtin_bit_cast(unsigned, f);
  u += 0x7FFFu + ((u >> 16) & 1u);
  return (unsigned short)(u >> 16);
}
DEV float bf2f(unsigned short h) {
  unsigned u = ((unsigned)h) << 16;
  return __builtin_bit_cast(float, u);
}

DEV void gload16(const unsigned short* g, unsigned short* lds) {
  __builtin_amdgcn_global_load_lds(
      (const __attribute__((address_space(1))) unsigned int*)g,
      (__attribute__((address_space(3))) unsigned int*)lds, 16, 0, 0);
}

// ---------------------------------------------------------------------------
// Shared 128x128 GEMM core, BK=64, 4 waves (2x2), mfma_f32_16x16x32_bf16.
// LDS tile is XOR-swizzled (T2, st-style): physical 16B chunk pc within a row
// holds logical chunk pc ^ (row&7). global_load_lds dest stays linear
// (wave-uniform base + lane*16); the SOURCE address is pre-swizzled; ds_read
// applies the same XOR (involution). 16-way bank conflict -> 2-way (free).
// ---------------------------------------------------------------------------
DEV void gemm_core(const unsigned short* __restrict__ Ab, int lda,
                   const unsigned short* __restrict__ Bb, int ldb,
                   unsigned short* lA, unsigned short* lB,
                   int m0, int n0, int nK, int w, int l,
                   f32x4 acc[4][4])
{
  const int wr = (w >> 1) * 64, wc = (w & 1) * 64;
  const int lan = l & 15, lgr = l >> 4;

  for (int kt = 0; kt < nK; ++kt) {
    const int k0 = kt * 64;
    __syncthreads();
#pragma unroll
    for (int i = 0; i < 4; ++i) {
      const int obb = i * 4096 + w * 1024;      // wave-uniform byte base
      const int ob  = obb + (l << 4);           // this lane's physical byte
      const int row = ob >> 7;                  // 128 B per row
      const int col = (((ob >> 4) & 7) ^ (row & 7)) << 3;  // logical elem col
      gload16(Ab + (size_t)(m0 + row) * lda + k0 + col, lA + (obb >> 1));
      gload16(Bb + (size_t)(n0 + row) * ldb + k0 + col, lB + (obb >> 1));
    }
    asm volatile("s_waitcnt vmcnt(0)" ::: "memory");
    __syncthreads();

#pragma unroll
    for (int ks = 0; ks < 2; ++ks) {
      bf16x8 av[4], bv[4];
#pragma unroll
      for (int m = 0; m < 4; ++m) {
        const int row = wr + m * 16 + lan;
        const int byte = ((row << 7) + (ks << 6) + (lgr << 4)) ^ ((row & 7) << 4);
        av[m] = *(const bf16x8*)((const char*)lA + byte);
      }
#pragma unroll
      for (int n = 0; n < 4; ++n) {
        const int row = wc + n * 16 + lan;
        const int byte = ((row << 7) + (ks << 6) + (lgr << 4)) ^ ((row & 7) << 4);
        bv[n] = *(const bf16x8*)((const char*)lB + byte);
      }
#pragma unroll
      for (int m = 0; m < 4; ++m)
#pragma unroll
        for (int n = 0; n < 4; ++n)
          acc[m][n] = __builtin_amdgcn_mfma_f32_16x16x32_bf16(av[m], bv[n], acc[m][n], 0, 0, 0);
    }
  }
}

// ---------------------------------------------------------------------------
// Generic batched GEMM: C[M,N] = A[M,K] @ Bt[N,K]. Batch z -> (bn,bh).
// EPI: 0=f32 out, 1=bf16 out, 2=bf16(bias+relu), 3=f32(bias)
// split-K: set Hb=nsplit, sAn=sBn=0, sAh=sBh=K_per_split, sC=M*N.
// ---------------------------------------------------------------------------
template <int EPI>
__global__ __launch_bounds__(256) void gemm_bt(
    const unsigned short* __restrict__ A, int lda, int sAn, int sAh,
    const unsigned short* __restrict__ B, int ldb, int sBn, int sBh,
    void* __restrict__ Cv, int ldc, int sC,
    const float* __restrict__ bias, int nK, int Hb)
{
  __shared__ unsigned short lA[128 * 64];
  __shared__ unsigned short lB[128 * 64];

  const int z = blockIdx.z;
  const int bn = z / Hb, bh = z % Hb;
  const unsigned short* Ab = A + (size_t)bn * sAn + (size_t)bh * sAh;
  const unsigned short* Bb = B + (size_t)bn * sBn + (size_t)bh * sBh;
  const int m0 = blockIdx.y * 128;
  const int n0 = blockIdx.x * 128;

  const int t = threadIdx.x;
  const int w = t >> 6, l = t & 63;
  const int wr = (w >> 1) * 64, wc = (w & 1) * 64;
  const int lan = l & 15, lgr = l >> 4;

  f32x4 acc[4][4];
#pragma unroll
  for (int m = 0; m < 4; ++m)
#pragma unroll
    for (int n = 0; n < 4; ++n) acc[m][n] = (f32x4){0.f, 0.f, 0.f, 0.f};

  gemm_core(Ab, lda, Bb, ldb, lA, lB, m0, n0, nK, w, l, acc);

  const int zc = z * sC;
#pragma unroll
  for (int m = 0; m < 4; ++m) {
    const int row = m0 + wr + m * 16 + lgr * 4;
#pragma unroll
    for (int n = 0; n < 4; ++n) {
      const int col = n0 + wc + n * 16 + lan;
      const float bcol = (EPI >= 2) ? bias[col] : 0.f;
#pragma unroll
      for (int e = 0; e < 4; ++e) {
        float v = acc[m][n][e];
        const size_t idx = (size_t)zc + (size_t)(row + e) * ldc + col;
        if (EPI == 0) {
          ((float*)Cv)[idx] = v;
        } else if (EPI == 1) {
          ((unsigned short*)Cv)[idx] = f2bf(v);
        } else if (EPI == 2) {
          v += bcol; v = v > 0.f ? v : 0.f;
          ((unsigned short*)Cv)[idx] = f2bf(v);
        } else {
          ((float*)Cv)[idx] = v + bcol;
        }
      }
    }
  }
}

// ---------------------------------------------------------------------------
// Fused projection GEMM: [cat(8192 rows) ; R(256 rows)] @ [Wk|Wv|Wq|Wr]^T
// Sparse block map (1296 blocks):
//   id<1024 : k/v cols (bx 0..15),  all cat rows (by 0..63)
//   id<1280 : q cols  (bx 16..23),  h rows only (by 32..63)
//   else    : r cols  (bx 24..31),  R rows (by 64..65)
// Epilogue routes to kbf / vbf / (qw,qr with biases) / rbf.
// ---------------------------------------------------------------------------
__global__ __launch_bounds__(256) void gemm_proj(
    const unsigned short* __restrict__ catA, const unsigned short* __restrict__ wt,
    unsigned short* __restrict__ kb, unsigned short* __restrict__ vb,
    unsigned short* __restrict__ qw, unsigned short* __restrict__ qr,
    unsigned short* __restrict__ rb,
    const float* __restrict__ rwb, const float* __restrict__ rrb)
{
  __shared__ unsigned short lA[128 * 64];
  __shared__ unsigned short lB[128 * 64];

  const int id = blockIdx.x;
  int by, bx;
  if (id < 1024)      { by = id >> 4;               bx = id & 15; }
  else if (id < 1280) { const int u = id - 1024; by = 32 + (u >> 3); bx = 16 + (u & 7); }
  else                { const int u = id - 1280; by = 64 + (u >> 3); bx = 24 + (u & 7); }
  const int m0 = by * 128, n0 = bx * 128;

  const int t = threadIdx.x;
  const int w = t >> 6, l = t & 63;
  const int wr = (w >> 1) * 64, wc = (w & 1) * 64;
  const int lan = l & 15, lgr = l >> 4;

  f32x4 acc[4][4];
#pragma unroll
  for (int m = 0; m < 4; ++m)
#pragma unroll
    for (int n = 0; n < 4; ++n) acc[m][n] = (f32x4){0.f, 0.f, 0.f, 0.f};

  gemm_core(catA, 1024, wt, 1024, lA, lB, m0, n0, 16, w, l, acc);

#pragma unroll
  for (int m = 0; m < 4; ++m) {
    const int row = m0 + wr + m * 16 + lgr * 4;
#pragma unroll
    for (int n = 0; n < 4; ++n) {
      const int col = n0 + wc + n * 16 + lan;
#pragma unroll
      for (int e = 0; e < 4; ++e) {
        const float v = acc[m][n][e];
        const int r = row + e;
        if (col < 1024) {
          kb[(size_t)r * 1024 + col] = f2bf(v);
        } else if (col < 2048) {
          vb[(size_t)r * 1024 + col - 1024] = f2bf(v);
        } else if (col < 3072) {
          const int c = col - 2048;
          const size_t o = (size_t)(r - 4096) * 1024 + c;
          qw[o] = f2bf(v + rwb[c]);
          qr[o] = f2bf(v + rrb[c]);
        } else {
          const int c = col - 3072;
          rb[(size_t)(r - 8192) * 1024 + c] = f2bf(v);
        }
      }
    }
  }
}

// ---------------------------------------------------------------------------
// PV: per batch z=(nn,hh): O[i,d] = sum_j P[i,j] * V[j,d]
// ---------------------------------------------------------------------------
__global__ __launch_bounds__(256) void pv_kernel(
    const unsigned short* __restrict__ P, const unsigned short* __restrict__ V,
    unsigned short* __restrict__ O)
{
  const int z = blockIdx.x;
  const int nn = z >> 4, hh = z & 15;
  const int t = threadIdx.x, w = t >> 6, l = t & 63;
  const int lan = l & 15, lgr = l >> 4;
  const int i0 = w * 32;
  const unsigned short* Pz = P + (size_t)z * (T_ * KLEN);
  const unsigned short* Vz = V + hh * DH_;

  f32x4 acc[2][4];
#pragma unroll
  for (int m = 0; m < 2; ++m)
#pragma unroll
    for (int n = 0; n < 4; ++n) acc[m][n] = (f32x4){0.f, 0.f, 0.f, 0.f};

  for (int ks = 0; ks < 8; ++ks) {
    const int kb = ks * 32 + lgr * 8;
    bf16x8 bv[4];
#pragma unroll
    for (int n = 0; n < 4; ++n) {
      const int d = n * 16 + lan;
      bf16x8 tmp;
#pragma unroll
      for (int jj = 0; jj < 8; ++jj)
        tmp[jj] = (short)Vz[(size_t)((kb + jj) * NE + nn) * 1024 + d];
      bv[n] = tmp;
    }
    bf16x8 av[2];
#pragma unroll
    for (int m = 0; m < 2; ++m)
      av[m] = *(const bf16x8*)&Pz[(size_t)(i0 + m * 16 + lan) * KLEN + kb];
#pragma unroll
    for (int m = 0; m < 2; ++m)
#pragma unroll
      for (int n = 0; n < 4; ++n)
        acc[m][n] = __builtin_amdgcn_mfma_f32_16x16x32_bf16(av[m], bv[n], acc[m][n], 0, 0, 0);
  }
#pragma unroll
  for (int m = 0; m < 2; ++m)
#pragma unroll
    for (int n = 0; n < 4; ++n)
#pragma unroll
      for (int e = 0; e < 4; ++e) {
        const int i = i0 + m * 16 + lgr * 4 + e;
        const int d = n * 16 + lan;
        O[(size_t)(i * NE + nn) * 1024 + hh * DH_ + d] = f2bf(acc[m][n][e]);
      }
}

// ---------------------------------------------------------------------------
// Masked softmax with rel_shift gather. One wave per (z, i) row.
// ---------------------------------------------------------------------------
__global__ __launch_bounds__(256) void softmax_kernel(
    const unsigned short* __restrict__ AC, const unsigned short* __restrict__ BD,
    const int* __restrict__ ep, unsigned short* __restrict__ P)
{
  const int g = blockIdx.x * 4 + (threadIdx.x >> 6);
  const int l = threadIdx.x & 63;
  const int z = g >> 7, i = g & 127;
  const int nn = z >> 4;
  const size_t base = (size_t)z * (T_ * KLEN) + (size_t)i * KLEN;
  const int j0 = l * 4;
  const int epi = ep[i * NE + nn];
  s16x4 ac4 = *(const s16x4*)&AC[base + j0];
  float sc[4];
#pragma unroll
  for (int q = 0; q < 4; ++q) {
    const int j = j0 + q;
    int jx = j + (T_ - 1) - i; if (jx > KLEN - 1) jx = KLEN - 1;
    const float bd = bf2f((unsigned short)BD[base + jx]);
    bool allow;
    if (j < M_) {
      allow = (epi == 0);
    } else {
      const int jp = j - M_;
      allow = (jp <= i) && (ep[jp * NE + nn] == epi);
    }
    const float v = (bf2f((unsigned short)ac4[q]) + bd) * 0.125f;
    sc[q] = allow ? v : -1e9f;
  }
  float mx = fmaxf(fmaxf(sc[0], sc[1]), fmaxf(sc[2], sc[3]));
#pragma unroll
  for (int o = 32; o; o >>= 1) mx = fmaxf(mx, __shfl_xor(mx, o));
  float p[4], sum = 0.f;
#pragma unroll
  for (int q = 0; q < 4; ++q) { p[q] = __expf(sc[q] - mx); sum += p[q]; }
#pragma unroll
  for (int o = 32; o; o >>= 1) sum += __shfl_xor(sum, o);
  const float inv = 1.f / sum;
  s16x4 o4;
#pragma unroll
  for (int q = 0; q < 4; ++q) o4[q] = (short)f2bf(p[q] * inv);
  *(s16x4*)&P[base + j0] = o4;
}

// ---------------------------------------------------------------------------
// W (Kd x Nd, f32 row-major) -> WT (Nd x Kd, bf16 row-major)
// ---------------------------------------------------------------------------
__global__ __launch_bounds__(256) void transpose_kernel(
    const float* __restrict__ W, unsigned short* __restrict__ WT, int Kd, int Nd)
{
  __shared__ float tile[32][33];
  const int tx = threadIdx.x & 31, ty = threadIdx.x >> 5;
  const int nIn = blockIdx.x * 32 + tx;
  const int kBase = blockIdx.y * 32;
#pragma unroll
  for (int r = 0; r < 32; r += 8)
    tile[ty + r][tx] = W[(size_t)(kBase + ty + r) * Nd + nIn];
  __syncthreads();
#pragma unroll
  for (int r = 0; r < 32; r += 8)
    WT[(size_t)(blockIdx.x * 32 + ty + r) * Kd + kBase + tx] = f2bf(tile[tx][ty + r]);
}

// cat lower half: cat[(j*32+nn)*1024 + d] = bf16(mems_l[nn][j][d] * masks[nn])
__global__ __launch_bounds__(256) void catmem_kernel(
    const float* __restrict__ mems_l, const float* __restrict__ masks,
    unsigned short* __restrict__ cat)
{
  const int idx = blockIdx.x * 256 + threadIdx.x;
  const int d = idx & 1023;
  const int r = idx >> 10;
  const int nn = r & 31, j = r >> 5;
  const float mk0 = masks[nn];
  cat[idx] = f2bf(mems_l[(size_t)(nn * M_ + j) * 1024 + d] * mk0);
}

// h = x + ctx (f32) and cat upper half (bf16)
__global__ __launch_bounds__(256) void hprep_kernel(
    const float* __restrict__ x, const float* __restrict__ ctx,
    float* __restrict__ h, unsigned short* __restrict__ catUp)
{
  const int idx = blockIdx.x * 256 + threadIdx.x;
  const float v = x[idx] + ctx[idx];
  h[idx] = v;
  catUp[idx] = f2bf(v);
}

// sinusoidal relative position table, bf16 (KLEN x 1024), into cat rows 8192+
__global__ __launch_bounds__(256) void rpos_kernel(unsigned short* __restrict__ R)
{
  const int idx = blockIdx.x * 256 + threadIdx.x;
  const int d = idx & 1023, j = idx >> 10;
  const float pos = (float)(KLEN - 1 - j);
  const int f = d & 511;
  const float inv_freq = __expf(-((float)(2 * f) * (1.f / 1024.f)) * 9.210340371976184f);
  const float ang = pos * inv_freq;
  const float v = (d < 512) ? sinf(ang) : cosf(ang);
  R[idx] = f2bf(v);
}

// episode counters
__global__ void ep_kernel(const float* __restrict__ masks, int* __restrict__ ep)
{
  const int nn = threadIdx.x;
  if (nn < NE) {
    int c = 0;
    for (int i = 0; i < T_; ++i) {
      c += (masks[i * NE + nn] == 0.f) ? 1 : 0;
      ep[i * NE + nn] = c;
    }
  }
}

// y = LN(a + p0 + p1 + bias) * g + b ; writes f32 (outf) and optional bf16
__global__ __launch_bounds__(256) void ln_kernel(
    const float* __restrict__ a, const float* __restrict__ p0,
    const float* __restrict__ p1, const float* __restrict__ bias,
    const float* __restrict__ g, const float* __restrict__ bb,
    float* __restrict__ outf, unsigned short* __restrict__ outbf)
{
  const int row = blockIdx.x;
  const int t = threadIdx.x, w = t >> 6, l = t & 63;
  const int c = t * 4;
  const size_t base = (size_t)row * 1024;
  f32x4 va = *(const f32x4*)&a[base + c];
  f32x4 v0 = *(const f32x4*)&p0[base + c];
  f32x4 v1 = *(const f32x4*)&p1[base + c];
  f32x4 v = va + v0 + v1;
  if (bias) {
    f32x4 vb = *(const f32x4*)&bias[c];
    v = v + vb;
  }
  float s = v[0] + v[1] + v[2] + v[3];
#pragma unroll
  for (int o = 32; o; o >>= 1) s += __shfl_xor(s, o);
  __shared__ float red[8];
  if (l == 0) red[w] = s;
  __syncthreads();
  s = red[0] + red[1] + red[2] + red[3];
  const float mu = s * (1.f / 1024.f);
  f32x4 dv = v - mu;
  float s2 = dv[0]*dv[0] + dv[1]*dv[1] + dv[2]*dv[2] + dv[3]*dv[3];
#pragma unroll
  for (int o = 32; o; o >>= 1) s2 += __shfl_xor(s2, o);
  if (l == 0) red[4 + w] = s2;
  __syncthreads();
  s2 = red[4] + red[5] + red[6] + red[7];
  const float inv = rsqrtf(s2 * (1.f / 1024.f) + 1e-5f);
  f32x4 y;
#pragma unroll
  for (int q = 0; q < 4; ++q) y[q] = dv[q] * inv * g[c + q] + bb[c + q];
  *(f32x4*)&outf[base + c] = y;
  if (outbf) {
    s16x4 o4;
#pragma unroll
    for (int q = 0; q < 4; ++q) o4[q] = (short)f2bf(y[q]);
    *(s16x4*)&outbf[base + c] = o4;
  }
}

// ---------------------------------------------------------------------------
extern "C" void kernel_launch(void* const* d_in, const int* in_sizes, int n_in,
                              void* d_out, int out_size, void* d_ws, size_t ws_size,
                              hipStream_t stream)
{
  (void)in_sizes; (void)n_in; (void)out_size; (void)ws_size;
  const float* x    = (const float*)d_in[0];
  const float* ctx  = (const float*)d_in[1];
  const float* mems = (const float*)d_in[2];
  const float* masks= (const float*)d_in[3];
  const float* Wq   = (const float*)d_in[4];
  const float* Wk   = (const float*)d_in[5];
  const float* Wv   = (const float*)d_in[6];
  const float* Wr   = (const float*)d_in[7];
  const float* Wo   = (const float*)d_in[8];
  const float* W1   = (const float*)d_in[9];
  const float* b1   = (const float*)d_in[10];
  const float* W2   = (const float*)d_in[11];
  const float* b2   = (const float*)d_in[12];
  const float* ln1g = (const float*)d_in[13];
  const float* ln1b = (const float*)d_in[14];
  const float* ln2g = (const float*)d_in[15];
  const float* ln2b = (const float*)d_in[16];
  const float* rwb  = (const float*)d_in[17];
  const float* rrb  = (const float*)d_in[18];

  char* ws = (char*)d_ws;
  size_t off = 0;
  auto alloc = [&](size_t bytes) {
    char* p = ws + off;
    off += (bytes + 255) & ~(size_t)255;
    return p;
  };
  unsigned short* wtAll = (unsigned short*)alloc(4096u * 1024 * 2);  // [Wk|Wv|Wq|Wr]^T
  unsigned short* wto = (unsigned short*)alloc(1024u * 1024 * 2);
  unsigned short* wt1 = (unsigned short*)alloc(4096u * 1024 * 2);
  unsigned short* wt2 = (unsigned short*)alloc(4096u * 1024 * 2);
  unsigned short* cat = (unsigned short*)alloc((size_t)(KLEN * NE + 256) * 1024 * 2); // + R rows
  unsigned short* rbf = (unsigned short*)alloc((size_t)KLEN * 1024 * 2);
  int*            epb = (int*)alloc((size_t)T_ * NE * 4);
  float*          h   = (float*)alloc((size_t)TN * 1024 * 4);
  float*          h1  = (float*)alloc((size_t)TN * 1024 * 4);
  unsigned short* qw  = (unsigned short*)alloc((size_t)TN * 1024 * 2);   // alias: h1_bf
  unsigned short* qr  = (unsigned short*)alloc((size_t)TN * 1024 * 2);
  unsigned short* kbf = (unsigned short*)alloc((size_t)KLEN * NE * 1024 * 2);
  unsigned short* vbf = (unsigned short*)alloc((size_t)KLEN * NE * 1024 * 2);
  unsigned short* ACb = (unsigned short*)alloc((size_t)NB * T_ * KLEN * 2); // alias: f1
  unsigned short* BDb = (unsigned short*)alloc((size_t)NB * T_ * KLEN * 2); // alias: part
  unsigned short* Pb  = (unsigned short*)alloc((size_t)NB * T_ * KLEN * 2);
  unsigned short* obf = (unsigned short*)alloc((size_t)TN * 1024 * 2);

  unsigned short* wtk = wtAll;
  unsigned short* wtv = wtAll + 1024u * 1024;
  unsigned short* wtq = wtAll + 2u * 1024 * 1024;
  unsigned short* wtr = wtAll + 3u * 1024 * 1024;
  unsigned short* catUp = cat + (size_t)M_ * NE * 1024;     // h rows (4096..8191)
  unsigned short* catR  = cat + (size_t)KLEN * NE * 1024;   // R rows (8192..8447)
  unsigned short* f1 = ACb;                 // W1 out (AC dead after softmax)
  float* part = (float*)BDb;                // split-K partials (BD dead after softmax)
  float* part1 = part + (size_t)TN * 1024;
  unsigned short* h1bf = qw;                // qw dead after AC gemm

  rpos_kernel<<<KLEN * 1024 / 256, 256, 0, stream>>>(catR);
  ep_kernel<<<1, 64, 0, stream>>>(masks, epb);
  hprep_kernel<<<TN * 1024 / 256, 256, 0, stream>>>(x, ctx, h, catUp);

  for (int l = 0; l < L_; ++l) {
    const size_t wOff = (size_t)l * 1024 * 1024;
    const size_t wOffBig = (size_t)l * 1024 * 4096;
    transpose_kernel<<<dim3(32, 32), 256, 0, stream>>>(Wk + wOff, wtk, 1024, 1024);
    transpose_kernel<<<dim3(32, 32), 256, 0, stream>>>(Wv + wOff, wtv, 1024, 1024);
    transpose_kernel<<<dim3(32, 32), 256, 0, stream>>>(Wq + wOff, wtq, 1024, 1024);
    transpose_kernel<<<dim3(32, 32), 256, 0, stream>>>(Wr + wOff, wtr, 1024, 1024);
    transpose_kernel<<<dim3(32, 32), 256, 0, stream>>>(Wo + wOff, wto, 1024, 1024);
    transpose_kernel<<<dim3(128, 32), 256, 0, stream>>>(W1 + wOffBig, wt1, 1024, 4096);
    transpose_kernel<<<dim3(32, 128), 256, 0, stream>>>(W2 + wOffBig, wt2, 4096, 1024);
    catmem_kernel<<<M_ * NE * 1024 / 256, 256, 0, stream>>>(
        mems + (size_t)l * NE * M_ * 1024, masks, cat);

    // fused k|v|q|r projection (1296 blocks)
    gemm_proj<<<1296, 256, 0, stream>>>(cat, wtAll, kbf, vbf, qw, qr, rbf, rwb, rrb);

    // AC / BD batched score GEMMs (batch z = nn*16+hh), K=64, M=128, N=256
    gemm_bt<1><<<dim3(2, 1, NB), 256, 0, stream>>>(qw, NE * 1024, 1024, 64,
                                                   kbf, NE * 1024, 1024, 64,
                                                   ACb, KLEN, T_ * KLEN, nullptr, 1, H_);
    gemm_bt<1><<<dim3(2, 1, NB), 256, 0, stream>>>(qr, NE * 1024, 1024, 64,
                                                   rbf, 1024, 0, 64,
                                                   BDb, KLEN, T_ * KLEN, nullptr, 1, H_);
    softmax_kernel<<<NB * T_ / 4, 256, 0, stream>>>(ACb, BDb, epb, Pb);
    pv_kernel<<<NB, 256, 0, stream>>>(Pb, vbf, obf);

    // output projection, split-K=2 -> f32 partials; reduce fused into LN1
    gemm_bt<0><<<dim3(8, 32, 2), 256, 0, stream>>>(obf, 1024, 0, 512,
                                                   wto, 1024, 0, 512,
                                                   part, 1024, TN * 1024, nullptr, 8, 2);
    ln_kernel<<<TN, 256, 0, stream>>>(h, part, part1, nullptr,
                                      ln1g + l * 1024, ln1b + l * 1024, h1, h1bf);

    // FFN
    gemm_bt<2><<<dim3(32, 32, 1), 256, 0, stream>>>(h1bf, 1024, 0, 0, wt1, 1024, 0, 0,
                                                    f1, 4096, 0, b1 + l * 4096, 16, 1);
    gemm_bt<0><<<dim3(8, 32, 2), 256, 0, stream>>>(f1, 4096, 0, 2048,
                                                   wt2, 4096, 0, 2048,
                                                   part, 1024, TN * 1024, nullptr, 32, 2);
    ln_kernel<<<TN, 256, 0, stream>>>(h1, part, part1, b2 + l * 1024,
                                      ln2g + l * 1024, ln2b + l * 1024,
                                      (l == L_ - 1) ? (float*)d_out : h, catUp);
  }
}

// Round 3
// 1939.431 us; speedup vs baseline: 1.3264x; 1.0247x over previous
//
#include <hip/hip_runtime.h>
#include <stdint.h>

#define DEV static __device__ __forceinline__

typedef __attribute__((ext_vector_type(4))) float f32x4;
typedef __attribute__((ext_vector_type(8))) short bf16x8;
typedef __attribute__((ext_vector_type(4))) short s16x4;

// dims
static constexpr int L_ = 6, T_ = 128, NE = 32, D_ = 1024, H_ = 16, DH_ = 64, M_ = 128, DI_ = 4096;
static constexpr int KLEN = M_ + T_;   // 256
static constexpr int TN = T_ * NE;     // 4096
static constexpr int NB = NE * H_;     // 512 attention batches

DEV unsigned short f2bf(float f) {
  unsigned u = __builtin_bit_cast(unsigned, f);
  u += 0x7FFFu + ((u >> 16) & 1u);
  return (unsigned short)(u >> 16);
}
DEV float bf2f(unsigned short h) {
  unsigned u = ((unsigned)h) << 16;
  return __builtin_bit_cast(float, u);
}

DEV void gload16(const unsigned short* g, unsigned short* lds) {
  __builtin_amdgcn_global_load_lds(
      (const __attribute__((address_space(1))) unsigned int*)g,
      (__attribute__((address_space(3))) unsigned int*)lds, 16, 0, 0);
}

// ---------------------------------------------------------------------------
// 128x128 tile core, BK=64, 4 waves (2x2), mfma_f32_16x16x32_bf16.
// T2 XOR-swizzle (both-sides): LDS dest linear, SOURCE pre-swizzled, ds_read
// applies same XOR. T3 minimum-2-phase: STAGE(t+1) issued before compute(t);
// one vmcnt(0)+barrier per K-step; LDS double-buffered (2x32KB).
// ---------------------------------------------------------------------------
DEV void stage128(const unsigned short* __restrict__ Ab, int lda,
                  const unsigned short* __restrict__ Bb, int ldb,
                  unsigned short* lA, unsigned short* lB,
                  int m0, int n0, int k0, int w, int l)
{
#pragma unroll
  for (int i = 0; i < 4; ++i) {
    const int obb = i * 4096 + w * 1024;      // wave-uniform byte base
    const int ob  = obb + (l << 4);           // this lane's physical byte
    const int row = ob >> 7;                  // 128 B per row
    const int col = (((ob >> 4) & 7) ^ (row & 7)) << 3;  // pre-swizzled src col
    gload16(Ab + (size_t)(m0 + row) * lda + k0 + col, lA + (obb >> 1));
    gload16(Bb + (size_t)(n0 + row) * ldb + k0 + col, lB + (obb >> 1));
  }
}

DEV void compute128(const unsigned short* lA, const unsigned short* lB,
                    int w, int l, f32x4 acc[4][4])
{
  const int wr = (w >> 1) * 64, wc = (w & 1) * 64;
  const int lan = l & 15, lgr = l >> 4;
#pragma unroll
  for (int ks = 0; ks < 2; ++ks) {
    bf16x8 av[4], bv[4];
#pragma unroll
    for (int m = 0; m < 4; ++m) {
      const int row = wr + m * 16 + lan;
      const int byte = ((row << 7) + (ks << 6) + (lgr << 4)) ^ ((row & 7) << 4);
      av[m] = *(const bf16x8*)((const char*)lA + byte);
    }
#pragma unroll
    for (int n = 0; n < 4; ++n) {
      const int row = wc + n * 16 + lan;
      const int byte = ((row << 7) + (ks << 6) + (lgr << 4)) ^ ((row & 7) << 4);
      bv[n] = *(const bf16x8*)((const char*)lB + byte);
    }
#pragma unroll
    for (int m = 0; m < 4; ++m)
#pragma unroll
      for (int n = 0; n < 4; ++n)
        acc[m][n] = __builtin_amdgcn_mfma_f32_16x16x32_bf16(av[m], bv[n], acc[m][n], 0, 0, 0);
  }
}

DEV void gemm128_2ph(const unsigned short* __restrict__ Ab, int lda,
                     const unsigned short* __restrict__ Bb, int ldb,
                     unsigned short (*shA)[8192], unsigned short (*shB)[8192],
                     int m0, int n0, int nK, int w, int l, f32x4 acc[4][4])
{
  stage128(Ab, lda, Bb, ldb, shA[0], shB[0], m0, n0, 0, w, l);
  asm volatile("s_waitcnt vmcnt(0)" ::: "memory");
  __syncthreads();
  int cur = 0;
  for (int kt = 0; kt < nK; ++kt) {
    if (kt + 1 < nK)
      stage128(Ab, lda, Bb, ldb, shA[cur ^ 1], shB[cur ^ 1], m0, n0, (kt + 1) * 64, w, l);
    compute128(shA[cur], shB[cur], w, l, acc);
    asm volatile("s_waitcnt vmcnt(0)" ::: "memory");
    __syncthreads();
    cur ^= 1;
  }
}

// ---------------------------------------------------------------------------
// Generic batched GEMM: C[M,N] = A[M,K] @ Bt[N,K]. Batch z -> (bn,bh).
// EPI: 0=f32 out, 1=bf16 out, 2=bf16(bias+relu), 3=f32(bias)
// split-K: Hb=nsplit, sAn=sBn=0, sAh=sBh=K_per_split, sC=M*N.
// ---------------------------------------------------------------------------
template <int EPI>
__global__ __launch_bounds__(256) void gemm_bt(
    const unsigned short* __restrict__ A, int lda, int sAn, int sAh,
    const unsigned short* __restrict__ B, int ldb, int sBn, int sBh,
    void* __restrict__ Cv, int ldc, int sC,
    const float* __restrict__ bias, int nK, int Hb)
{
  __shared__ unsigned short shA[2][8192];
  __shared__ unsigned short shB[2][8192];

  const int z = blockIdx.z;
  const int bn = z / Hb, bh = z % Hb;
  const unsigned short* Ab = A + (size_t)bn * sAn + (size_t)bh * sAh;
  const unsigned short* Bb = B + (size_t)bn * sBn + (size_t)bh * sBh;
  const int m0 = blockIdx.y * 128;
  const int n0 = blockIdx.x * 128;

  const int t = threadIdx.x;
  const int w = t >> 6, l = t & 63;
  const int wr = (w >> 1) * 64, wc = (w & 1) * 64;
  const int lan = l & 15, lgr = l >> 4;

  f32x4 acc[4][4];
#pragma unroll
  for (int m = 0; m < 4; ++m)
#pragma unroll
    for (int n = 0; n < 4; ++n) acc[m][n] = (f32x4){0.f, 0.f, 0.f, 0.f};

  gemm128_2ph(Ab, lda, Bb, ldb, shA, shB, m0, n0, nK, w, l, acc);

  const int zc = z * sC;
#pragma unroll
  for (int m = 0; m < 4; ++m) {
    const int row = m0 + wr + m * 16 + lgr * 4;
#pragma unroll
    for (int n = 0; n < 4; ++n) {
      const int col = n0 + wc + n * 16 + lan;
      const float bcol = (EPI >= 2) ? bias[col] : 0.f;
#pragma unroll
      for (int e = 0; e < 4; ++e) {
        float v = acc[m][n][e];
        const size_t idx = (size_t)zc + (size_t)(row + e) * ldc + col;
        if (EPI == 0) {
          ((float*)Cv)[idx] = v;
        } else if (EPI == 1) {
          ((unsigned short*)Cv)[idx] = f2bf(v);
        } else if (EPI == 2) {
          v += bcol; v = v > 0.f ? v : 0.f;
          ((unsigned short*)Cv)[idx] = f2bf(v);
        } else {
          ((float*)Cv)[idx] = v + bcol;
        }
      }
    }
  }
}

// ---------------------------------------------------------------------------
// Fused projection GEMM: [cat(8192 rows) ; R(256 rows)] @ [Wk|Wv|Wq|Wr]^T
// ---------------------------------------------------------------------------
__global__ __launch_bounds__(256) void gemm_proj(
    const unsigned short* __restrict__ catA, const unsigned short* __restrict__ wt,
    unsigned short* __restrict__ kb, unsigned short* __restrict__ vb,
    unsigned short* __restrict__ qw, unsigned short* __restrict__ qr,
    unsigned short* __restrict__ rb,
    const float* __restrict__ rwb, const float* __restrict__ rrb)
{
  __shared__ unsigned short shA[2][8192];
  __shared__ unsigned short shB[2][8192];

  const int id = blockIdx.x;
  int by, bx;
  if (id < 1024)      { by = id >> 4;               bx = id & 15; }
  else if (id < 1280) { const int u = id - 1024; by = 32 + (u >> 3); bx = 16 + (u & 7); }
  else                { const int u = id - 1280; by = 64 + (u >> 3); bx = 24 + (u & 7); }
  const int m0 = by * 128, n0 = bx * 128;

  const int t = threadIdx.x;
  const int w = t >> 6, l = t & 63;
  const int wr = (w >> 1) * 64, wc = (w & 1) * 64;
  const int lan = l & 15, lgr = l >> 4;

  f32x4 acc[4][4];
#pragma unroll
  for (int m = 0; m < 4; ++m)
#pragma unroll
    for (int n = 0; n < 4; ++n) acc[m][n] = (f32x4){0.f, 0.f, 0.f, 0.f};

  gemm128_2ph(catA, 1024, wt, 1024, shA, shB, m0, n0, 16, w, l, acc);

#pragma unroll
  for (int m = 0; m < 4; ++m) {
    const int row = m0 + wr + m * 16 + lgr * 4;
#pragma unroll
    for (int n = 0; n < 4; ++n) {
      const int col = n0 + wc + n * 16 + lan;
#pragma unroll
      for (int e = 0; e < 4; ++e) {
        const float v = acc[m][n][e];
        const int r = row + e;
        if (col < 1024) {
          kb[(size_t)r * 1024 + col] = f2bf(v);
        } else if (col < 2048) {
          vb[(size_t)r * 1024 + col - 1024] = f2bf(v);
        } else if (col < 3072) {
          const int c = col - 2048;
          const size_t o = (size_t)(r - 4096) * 1024 + c;
          qw[o] = f2bf(v + rwb[c]);
          qr[o] = f2bf(v + rrb[c]);
        } else {
          const int c = col - 3072;
          rb[(size_t)(r - 8192) * 1024 + c] = f2bf(v);
        }
      }
    }
  }
}

// ---------------------------------------------------------------------------
// Fused AC+BD score GEMMs: grid (4, 512). bx<2 -> AC cols, bx>=2 -> BD cols.
// z = nn*16+hh. M=128 (T), N=256 (klen), K=64. nK=1.
// ---------------------------------------------------------------------------
__global__ __launch_bounds__(256) void gemm_scores(
    const unsigned short* __restrict__ qw, const unsigned short* __restrict__ qr,
    const unsigned short* __restrict__ kbf, const unsigned short* __restrict__ rbf,
    unsigned short* __restrict__ AC, unsigned short* __restrict__ BD)
{
  __shared__ unsigned short shA[2][8192];
  __shared__ unsigned short shB[2][8192];

  const int bx = blockIdx.x;
  const int z = blockIdx.y;
  const int nn = z >> 4, hh = z & 15;
  const bool isBD = bx >= 2;
  const int n0 = (bx & 1) * 128;
  const unsigned short* Ab = (isBD ? qr : qw) + (size_t)nn * 1024 + hh * 64;
  const unsigned short* Bb = isBD ? (rbf + hh * 64)
                                  : (kbf + (size_t)nn * 1024 + hh * 64);
  const int ldb = isBD ? 1024 : (NE * 1024);
  unsigned short* C = (isBD ? BD : AC) + (size_t)z * (T_ * KLEN);

  const int t = threadIdx.x;
  const int w = t >> 6, l = t & 63;
  const int wr = (w >> 1) * 64, wc = (w & 1) * 64;
  const int lan = l & 15, lgr = l >> 4;

  f32x4 acc[4][4];
#pragma unroll
  for (int m = 0; m < 4; ++m)
#pragma unroll
    for (int n = 0; n < 4; ++n) acc[m][n] = (f32x4){0.f, 0.f, 0.f, 0.f};

  gemm128_2ph(Ab, NE * 1024, Bb, ldb, shA, shB, 0, n0, 1, w, l, acc);

#pragma unroll
  for (int m = 0; m < 4; ++m) {
    const int row = wr + m * 16 + lgr * 4;
#pragma unroll
    for (int n = 0; n < 4; ++n) {
      const int col = n0 + wc + n * 16 + lan;
#pragma unroll
      for (int e = 0; e < 4; ++e)
        C[(size_t)(row + e) * KLEN + col] = f2bf(acc[m][n][e]);
    }
  }
}

// ---------------------------------------------------------------------------
// PV: per batch z=(nn,hh): O[i,d] = sum_j P[i,j] * V[j,d]
// ---------------------------------------------------------------------------
__global__ __launch_bounds__(256) void pv_kernel(
    const unsigned short* __restrict__ P, const unsigned short* __restrict__ V,
    unsigned short* __restrict__ O)
{
  const int z = blockIdx.x;
  const int nn = z >> 4, hh = z & 15;
  const int t = threadIdx.x, w = t >> 6, l = t & 63;
  const int lan = l & 15, lgr = l >> 4;
  const int i0 = w * 32;
  const unsigned short* Pz = P + (size_t)z * (T_ * KLEN);
  const unsigned short* Vz = V + hh * DH_;

  f32x4 acc[2][4];
#pragma unroll
  for (int m = 0; m < 2; ++m)
#pragma unroll
    for (int n = 0; n < 4; ++n) acc[m][n] = (f32x4){0.f, 0.f, 0.f, 0.f};

  for (int ks = 0; ks < 8; ++ks) {
    const int kb = ks * 32 + lgr * 8;
    bf16x8 bv[4];
#pragma unroll
    for (int n = 0; n < 4; ++n) {
      const int d = n * 16 + lan;
      bf16x8 tmp;
#pragma unroll
      for (int jj = 0; jj < 8; ++jj)
        tmp[jj] = (short)Vz[(size_t)((kb + jj) * NE + nn) * 1024 + d];
      bv[n] = tmp;
    }
    bf16x8 av[2];
#pragma unroll
    for (int m = 0; m < 2; ++m)
      av[m] = *(const bf16x8*)&Pz[(size_t)(i0 + m * 16 + lan) * KLEN + kb];
#pragma unroll
    for (int m = 0; m < 2; ++m)
#pragma unroll
      for (int n = 0; n < 4; ++n)
        acc[m][n] = __builtin_amdgcn_mfma_f32_16x16x32_bf16(av[m], bv[n], acc[m][n], 0, 0, 0);
  }
#pragma unroll
  for (int m = 0; m < 2; ++m)
#pragma unroll
    for (int n = 0; n < 4; ++n)
#pragma unroll
      for (int e = 0; e < 4; ++e) {
        const int i = i0 + m * 16 + lgr * 4 + e;
        const int d = n * 16 + lan;
        O[(size_t)(i * NE + nn) * 1024 + hh * DH_ + d] = f2bf(acc[m][n][e]);
      }
}

// ---------------------------------------------------------------------------
// Masked softmax with rel_shift gather. One wave per (z, i) row.
// ---------------------------------------------------------------------------
__global__ __launch_bounds__(256) void softmax_kernel(
    const unsigned short* __restrict__ AC, const unsigned short* __restrict__ BD,
    const int* __restrict__ ep, unsigned short* __restrict__ P)
{
  const int g = blockIdx.x * 4 + (threadIdx.x >> 6);
  const int l = threadIdx.x & 63;
  const int z = g >> 7, i = g & 127;
  const int nn = z >> 4;
  const size_t base = (size_t)z * (T_ * KLEN) + (size_t)i * KLEN;
  const int j0 = l * 4;
  const int epi = ep[i * NE + nn];
  s16x4 ac4 = *(const s16x4*)&AC[base + j0];
  float sc[4];
#pragma unroll
  for (int q = 0; q < 4; ++q) {
    const int j = j0 + q;
    int jx = j + (T_ - 1) - i; if (jx > KLEN - 1) jx = KLEN - 1;
    const float bd = bf2f((unsigned short)BD[base + jx]);
    bool allow;
    if (j < M_) {
      allow = (epi == 0);
    } else {
      const int jp = j - M_;
      allow = (jp <= i) && (ep[jp * NE + nn] == epi);
    }
    const float v = (bf2f((unsigned short)ac4[q]) + bd) * 0.125f;
    sc[q] = allow ? v : -1e9f;
  }
  float mx = fmaxf(fmaxf(sc[0], sc[1]), fmaxf(sc[2], sc[3]));
#pragma unroll
  for (int o = 32; o; o >>= 1) mx = fmaxf(mx, __shfl_xor(mx, o));
  float p[4], sum = 0.f;
#pragma unroll
  for (int q = 0; q < 4; ++q) { p[q] = __expf(sc[q] - mx); sum += p[q]; }
#pragma unroll
  for (int o = 32; o; o >>= 1) sum += __shfl_xor(sum, o);
  const float inv = 1.f / sum;
  s16x4 o4;
#pragma unroll
  for (int q = 0; q < 4; ++q) o4[q] = (short)f2bf(p[q] * inv);
  *(s16x4*)&P[base + j0] = o4;
}

// ---------------------------------------------------------------------------
// W (Kd x Nd, f32 row-major) -> WT (Nd x Kd, bf16 row-major)
// ---------------------------------------------------------------------------
__global__ __launch_bounds__(256) void transpose_kernel(
    const float* __restrict__ W, unsigned short* __restrict__ WT, int Kd, int Nd)
{
  __shared__ float tile[32][33];
  const int tx = threadIdx.x & 31, ty = threadIdx.x >> 5;
  const int nIn = blockIdx.x * 32 + tx;
  const int kBase = blockIdx.y * 32;
#pragma unroll
  for (int r = 0; r < 32; r += 8)
    tile[ty + r][tx] = W[(size_t)(kBase + ty + r) * Nd + nIn];
  __syncthreads();
#pragma unroll
  for (int r = 0; r < 32; r += 8)
    WT[(size_t)(blockIdx.x * 32 + ty + r) * Kd + kBase + tx] = f2bf(tile[tx][ty + r]);
}

// cat lower half: cat[(j*32+nn)*1024 + d] = bf16(mems_l[nn][j][d] * masks[nn])
__global__ __launch_bounds__(256) void catmem_kernel(
    const float* __restrict__ mems_l, const float* __restrict__ masks,
    unsigned short* __restrict__ cat)
{
  const int idx = blockIdx.x * 256 + threadIdx.x;
  const int d = idx & 1023;
  const int r = idx >> 10;
  const int nn = r & 31, j = r >> 5;
  const float mk0 = masks[nn];
  cat[idx] = f2bf(mems_l[(size_t)(nn * M_ + j) * 1024 + d] * mk0);
}

// h = x + ctx (f32) and cat upper half (bf16)
__global__ __launch_bounds__(256) void hprep_kernel(
    const float* __restrict__ x, const float* __restrict__ ctx,
    float* __restrict__ h, unsigned short* __restrict__ catUp)
{
  const int idx = blockIdx.x * 256 + threadIdx.x;
  const float v = x[idx] + ctx[idx];
  h[idx] = v;
  catUp[idx] = f2bf(v);
}

// sinusoidal relative position table, bf16 (KLEN x 1024)
__global__ __launch_bounds__(256) void rpos_kernel(unsigned short* __restrict__ R)
{
  const int idx = blockIdx.x * 256 + threadIdx.x;
  const int d = idx & 1023, j = idx >> 10;
  const float pos = (float)(KLEN - 1 - j);
  const int f = d & 511;
  const float inv_freq = __expf(-((float)(2 * f) * (1.f / 1024.f)) * 9.210340371976184f);
  const float ang = pos * inv_freq;
  const float v = (d < 512) ? sinf(ang) : cosf(ang);
  R[idx] = f2bf(v);
}

// episode counters
__global__ void ep_kernel(const float* __restrict__ masks, int* __restrict__ ep)
{
  const int nn = threadIdx.x;
  if (nn < NE) {
    int c = 0;
    for (int i = 0; i < T_; ++i) {
      c += (masks[i * NE + nn] == 0.f) ? 1 : 0;
      ep[i * NE + nn] = c;
    }
  }
}

// y = LN(a + p0 + p1 + bias) * g + b ; writes f32 (outf) and optional bf16
__global__ __launch_bounds__(256) void ln_kernel(
    const float* __restrict__ a, const float* __restrict__ p0,
    const float* __restrict__ p1, const float* __restrict__ bias,
    const float* __restrict__ g, const float* __restrict__ bb,
    float* __restrict__ outf, unsigned short* __restrict__ outbf)
{
  const int row = blockIdx.x;
  const int t = threadIdx.x, w = t >> 6, l = t & 63;
  const int c = t * 4;
  const size_t base = (size_t)row * 1024;
  f32x4 va = *(const f32x4*)&a[base + c];
  f32x4 v0 = *(const f32x4*)&p0[base + c];
  f32x4 v1 = *(const f32x4*)&p1[base + c];
  f32x4 v = va + v0 + v1;
  if (bias) {
    f32x4 vb = *(const f32x4*)&bias[c];
    v = v + vb;
  }
  float s = v[0] + v[1] + v[2] + v[3];
#pragma unroll
  for (int o = 32; o; o >>= 1) s += __shfl_xor(s, o);
  __shared__ float red[8];
  if (l == 0) red[w] = s;
  __syncthreads();
  s = red[0] + red[1] + red[2] + red[3];
  const float mu = s * (1.f / 1024.f);
  f32x4 dv = v - mu;
  float s2 = dv[0]*dv[0] + dv[1]*dv[1] + dv[2]*dv[2] + dv[3]*dv[3];
#pragma unroll
  for (int o = 32; o; o >>= 1) s2 += __shfl_xor(s2, o);
  if (l == 0) red[4 + w] = s2;
  __syncthreads();
  s2 = red[4] + red[5] + red[6] + red[7];
  const float inv = rsqrtf(s2 * (1.f / 1024.f) + 1e-5f);
  f32x4 y;
#pragma unroll
  for (int q = 0; q < 4; ++q) y[q] = dv[q] * inv * g[c + q] + bb[c + q];
  *(f32x4*)&outf[base + c] = y;
  if (outbf) {
    s16x4 o4;
#pragma unroll
    for (int q = 0; q < 4; ++q) o4[q] = (short)f2bf(y[q]);
    *(s16x4*)&outbf[base + c] = o4;
  }
}

// ---------------------------------------------------------------------------
extern "C" void kernel_launch(void* const* d_in, const int* in_sizes, int n_in,
                              void* d_out, int out_size, void* d_ws, size_t ws_size,
                              hipStream_t stream)
{
  (void)in_sizes; (void)n_in; (void)out_size; (void)ws_size;
  const float* x    = (const float*)d_in[0];
  const float* ctx  = (const float*)d_in[1];
  const float* mems = (const float*)d_in[2];
  const float* masks= (const float*)d_in[3];
  const float* Wq   = (const float*)d_in[4];
  const float* Wk   = (const float*)d_in[5];
  const float* Wv   = (const float*)d_in[6];
  const float* Wr   = (const float*)d_in[7];
  const float* Wo   = (const float*)d_in[8];
  const float* W1   = (const float*)d_in[9];
  const float* b1   = (const float*)d_in[10];
  const float* W2   = (const float*)d_in[11];
  const float* b2   = (const float*)d_in[12];
  const float* ln1g = (const float*)d_in[13];
  const float* ln1b = (const float*)d_in[14];
  const float* ln2g = (const float*)d_in[15];
  const float* ln2b = (const float*)d_in[16];
  const float* rwb  = (const float*)d_in[17];
  const float* rrb  = (const float*)d_in[18];

  char* ws = (char*)d_ws;
  size_t off = 0;
  auto alloc = [&](size_t bytes) {
    char* p = ws + off;
    off += (bytes + 255) & ~(size_t)255;
    return p;
  };
  unsigned short* wtAll = (unsigned short*)alloc(4096u * 1024 * 2);  // [Wk|Wv|Wq|Wr]^T
  unsigned short* wto = (unsigned short*)alloc(1024u * 1024 * 2);
  unsigned short* wt1 = (unsigned short*)alloc(4096u * 1024 * 2);
  unsigned short* wt2 = (unsigned short*)alloc(4096u * 1024 * 2);
  unsigned short* cat = (unsigned short*)alloc((size_t)(KLEN * NE + 256) * 1024 * 2); // + R rows
  unsigned short* rbf = (unsigned short*)alloc((size_t)KLEN * 1024 * 2);
  int*            epb = (int*)alloc((size_t)T_ * NE * 4);
  float*          h   = (float*)alloc((size_t)TN * 1024 * 4);
  float*          h1  = (float*)alloc((size_t)TN * 1024 * 4);
  unsigned short* qw  = (unsigned short*)alloc((size_t)TN * 1024 * 2);   // alias: h1_bf
  unsigned short* qr  = (unsigned short*)alloc((size_t)TN * 1024 * 2);
  unsigned short* kbf = (unsigned short*)alloc((size_t)KLEN * NE * 1024 * 2);
  unsigned short* vbf = (unsigned short*)alloc((size_t)KLEN * NE * 1024 * 2);
  unsigned short* ACb = (unsigned short*)alloc((size_t)NB * T_ * KLEN * 2); // alias: f1
  unsigned short* BDb = (unsigned short*)alloc((size_t)NB * T_ * KLEN * 2); // alias: part
  unsigned short* Pb  = (unsigned short*)alloc((size_t)NB * T_ * KLEN * 2);
  unsigned short* obf = (unsigned short*)alloc((size_t)TN * 1024 * 2);

  unsigned short* wtk = wtAll;
  unsigned short* wtv = wtAll + 1024u * 1024;
  unsigned short* wtq = wtAll + 2u * 1024 * 1024;
  unsigned short* wtr = wtAll + 3u * 1024 * 1024;
  unsigned short* catUp = cat + (size_t)M_ * NE * 1024;     // h rows (4096..8191)
  unsigned short* catR  = cat + (size_t)KLEN * NE * 1024;   // R rows (8192..8447)
  unsigned short* f1 = ACb;                 // W1 out (AC dead after softmax)
  float* part = (float*)BDb;                // split-K partials (BD dead after softmax)
  float* part1 = part + (size_t)TN * 1024;
  unsigned short* h1bf = qw;                // qw dead after scores gemm

  rpos_kernel<<<KLEN * 1024 / 256, 256, 0, stream>>>(catR);
  ep_kernel<<<1, 64, 0, stream>>>(masks, epb);
  hprep_kernel<<<TN * 1024 / 256, 256, 0, stream>>>(x, ctx, h, catUp);

  for (int l = 0; l < L_; ++l) {
    const size_t wOff = (size_t)l * 1024 * 1024;
    const size_t wOffBig = (size_t)l * 1024 * 4096;
    transpose_kernel<<<dim3(32, 32), 256, 0, stream>>>(Wk + wOff, wtk, 1024, 1024);
    transpose_kernel<<<dim3(32, 32), 256, 0, stream>>>(Wv + wOff, wtv, 1024, 1024);
    transpose_kernel<<<dim3(32, 32), 256, 0, stream>>>(Wq + wOff, wtq, 1024, 1024);
    transpose_kernel<<<dim3(32, 32), 256, 0, stream>>>(Wr + wOff, wtr, 1024, 1024);
    transpose_kernel<<<dim3(32, 32), 256, 0, stream>>>(Wo + wOff, wto, 1024, 1024);
    transpose_kernel<<<dim3(128, 32), 256, 0, stream>>>(W1 + wOffBig, wt1, 1024, 4096);
    transpose_kernel<<<dim3(32, 128), 256, 0, stream>>>(W2 + wOffBig, wt2, 4096, 1024);
    catmem_kernel<<<M_ * NE * 1024 / 256, 256, 0, stream>>>(
        mems + (size_t)l * NE * M_ * 1024, masks, cat);

    // fused k|v|q|r projection (1296 blocks)
    gemm_proj<<<1296, 256, 0, stream>>>(cat, wtAll, kbf, vbf, qw, qr, rbf, rwb, rrb);

    // fused AC+BD score GEMMs (one launch, 2048 blocks)
    gemm_scores<<<dim3(4, 512), 256, 0, stream>>>(qw, qr, kbf, rbf, ACb, BDb);

    softmax_kernel<<<NB * T_ / 4, 256, 0, stream>>>(ACb, BDb, epb, Pb);
    pv_kernel<<<NB, 256, 0, stream>>>(Pb, vbf, obf);

    // output projection, split-K=2 -> f32 partials; reduce fused into LN1
    gemm_bt<0><<<dim3(8, 32, 2), 256, 0, stream>>>(obf, 1024, 0, 512,
                                                   wto, 1024, 0, 512,
                                                   part, 1024, TN * 1024, nullptr, 8, 2);
    ln_kernel<<<TN, 256, 0, stream>>>(h, part, part1, nullptr,
                                      ln1g + l * 1024, ln1b + l * 1024, h1, h1bf);

    // FFN
    gemm_bt<2><<<dim3(32, 32, 1), 256, 0, stream>>>(h1bf, 1024, 0, 0, wt1, 1024, 0, 0,
                                                    f1, 4096, 0, b1 + l * 4096, 16, 1);
    gemm_bt<0><<<dim3(8, 32, 2), 256, 0, stream>>>(f1, 4096, 0, 2048,
                                                   wt2, 4096, 0, 2048,
                                                   part, 1024, TN * 1024, nullptr, 32, 2);
    ln_kernel<<<TN, 256, 0, stream>>>(h1, part, part1, b2 + l * 1024,
                                      ln2g + l * 1024, ln2b + l * 1024,
                                      (l == L_ - 1) ? (float*)d_out : h, catUp);
  }
}